// Round 3
// baseline (508.249 us; speedup 1.0000x reference)
//
#include <hip/hip_runtime.h>
#include <hip/hip_bf16.h>

#define NLAYERS 3
#define BB 32
#define LL 336
#define LP 352                 // K-padded stride for Tb16 / W1t / p1wb (zeros in pad)
#define NN 321
#define EE 4
#define DHID 512
#define PP 96
#define STOT (BB*NN*LL)        // 3451392
#define MROWS (BB*NN)          // 10272
#define BPN ((size_t)BB*PP*NN) // 986112

typedef __attribute__((ext_vector_type(8))) short short8;
typedef __attribute__((ext_vector_type(4))) float float4v;

union BF { __hip_bfloat16 h; short s; };

__device__ __forceinline__ short f2b(float f) { BF u; u.h = __float2bfloat16(f); return u.s; }

__device__ __forceinline__ float fast_tanh(float y) {
    float e = __expf(2.0f * y);
    return 1.0f - 2.0f / (e + 1.0f);   // exact limits at +-inf
}
__device__ __forceinline__ float gelu_f(float x) {
    return 0.5f * x * (1.0f + fast_tanh(0.7978845608028654f * (x + 0.044715f * x * x * x)));
}
__device__ __forceinline__ float softplus_f(float x) {
    return fmaxf(x, 0.0f) + log1pf(expf(-fabsf(x)));
}

// ---------------- prep: weight transpose/convert + pcvt + RevIN stats + zeroing ----------------
// flat grid 1549: [0,576) W1-trans, [576,1152) W2-trans, [1152,1344) revin_stats(+zero G0/G1/LOSS),
// [1344,1549) pcvt.
__global__ __launch_bounds__(256) void prep_kernel(
    const float* __restrict__ x, const float* __restrict__ W1, const float* __restrict__ W2,
    const float* __restrict__ p1w, const float* __restrict__ p2w,
    float* __restrict__ MU, float* __restrict__ IV, float* __restrict__ LOSS,
    float* __restrict__ G0, float* __restrict__ G1,
    short* __restrict__ W1t, short* __restrict__ W2t,
    short* __restrict__ p1wb, short* __restrict__ p2wb)
{
    __shared__ short Ws[64][72];
    __shared__ float Ss[4][64], Sq[4][64];
    int idx = blockIdx.x, tid = threadIdx.x;
    if (idx < 1152) {
        const float* src; short* dst; int K, D, KS, bx, by;
        if (idx < 576) {
            int le = idx / 48, r = idx % 48;
            src = W1 + (size_t)le * LL * DHID; dst = W1t + (size_t)le * DHID * LP;
            K = LL; D = DHID; KS = LP; bx = r % 8; by = r / 8;
        } else {
            int s2 = idx - 576; int le = s2 / 48, r = s2 % 48;
            src = W2 + (size_t)le * DHID * LL; dst = W2t + (size_t)le * LL * DHID;
            K = DHID; D = LL; KS = DHID; bx = r % 6; by = r / 6;
        }
        int d0 = bx * 64, k0 = by * 64;
        #pragma unroll
        for (int i = 0; i < 16; ++i) {
            int lin = tid + i * 256;
            int ki = lin >> 6, dj = lin & 63;
            int k = k0 + ki, d = d0 + dj;
            Ws[ki][dj] = (k < K && d < D) ? f2b(src[(size_t)k * D + d]) : (short)0;
        }
        __syncthreads();
        int di = tid >> 2, d = d0 + di;
        if (d >= D) return;
        #pragma unroll
        for (int kp = 0; kp < 2; ++kp) {
            int kj = ((tid & 3) + 4 * kp) * 8;
            if (k0 + kj >= KS) continue;
            union { short s[8]; uint4 u; } pk;
            #pragma unroll
            for (int j = 0; j < 8; ++j) pk.s[j] = Ws[kj + j][di];
            *(uint4*)(dst + (size_t)d * KS + k0 + kj) = pk.u;
        }
    } else if (idx < 1344) {
        int q = idx - 1152;
        int b = q / 6, nt = q % 6;
        if (tid < 56) { G0[q * 56 + tid] = 0.0f; G1[q * 56 + tid] = 0.0f; }  // 192*56 = BB*LL
        if (q == 0 && tid < 8) LOSS[tid] = 0.0f;
        int ni = tid & 63, lc = tid >> 6;
        int n = nt * 64 + ni;
        float s = 0.f, ss = 0.f;
        if (n < NN) {
            const float* xp = x + ((size_t)b * LL + lc * 84) * NN + n;
            for (int l = 0; l < 84; ++l, xp += NN) {
                float v = *xp; s += v; ss = fmaf(v, v, ss);
            }
        }
        Ss[lc][ni] = s; Sq[lc][ni] = ss;
        __syncthreads();
        if (lc == 0 && n < NN) {
            float st = ((Ss[0][ni] + Ss[1][ni]) + Ss[2][ni]) + Ss[3][ni];
            float sq = ((Sq[0][ni] + Sq[1][ni]) + Sq[2][ni]) + Sq[3][ni];
            float mu  = st * (1.0f / LL);
            float var = sq * (1.0f / LL) - mu * mu;   // ddof=0
            MU[b * NN + n] = mu;
            IV[b * NN + n] = 1.0f / sqrtf(var + 1e-5f);
        }
    } else {
        int i = (idx - 1344) * 256 + tid;
        if (i < PP * LP) {
            int n = i / LP, k = i - n * LP;
            p1wb[i] = (k < LL) ? f2b(p1w[n * LL + k]) : (short)0;
        } else if (i < PP * LP + 2 * PP * PP) {
            int j = i - PP * LP;
            p2wb[j] = f2b(p2w[j]);
        }
    }
}

// ---------------- RevIN transpose+normalize + layer-0 gate-sum accumulation ----------------
__global__ __launch_bounds__(256) void revin_tn(
    const float* __restrict__ x, const float* __restrict__ MU, const float* __restrict__ IV,
    float* __restrict__ T, short* __restrict__ Tb16, float* __restrict__ G0)
{
    int b = blockIdx.x, nt = blockIdx.y, lt = blockIdx.z;
    int n0 = nt * 64, l0 = lt * 48;
    __shared__ float Ls[48][65];
    __shared__ float Vs[48][65];
    int tid = threadIdx.x;
    #pragma unroll
    for (int i = 0; i < 12; ++i) {
        int lin = tid + i * 256;
        int li = lin >> 6, ni = lin & 63;
        int n = n0 + ni;
        Ls[li][ni] = (n < NN) ? x[((size_t)b * LL + l0 + li) * NN + n] : 0.f;
    }
    __syncthreads();
    int r = tid >> 2, q = tid & 3;
    int n = n0 + r;
    bool valid = (n < NN);
    float mu = 0.f, iv = 0.f;
    if (valid) { mu = MU[b * NN + n]; iv = IV[b * NN + n]; }
    size_t rowf = (size_t)(b * NN + (valid ? n : 0)) * LL + l0;
    size_t rowb = (size_t)(b * NN + (valid ? n : 0)) * LP + l0;
    #pragma unroll
    for (int k = 0; k < 3; ++k) {
        int c = (q + 4 * k) * 4;
        float4 v;
        v.x = (Ls[c    ][r] - mu) * iv;
        v.y = (Ls[c + 1][r] - mu) * iv;
        v.z = (Ls[c + 2][r] - mu) * iv;
        v.w = (Ls[c + 3][r] - mu) * iv;
        Vs[c][r] = v.x; Vs[c + 1][r] = v.y; Vs[c + 2][r] = v.z; Vs[c + 3][r] = v.w;
        if (valid) {
            *(float4*)&T[rowf + c] = v;
            union { short s[4]; uint2 u; } pk;
            pk.s[0] = f2b(v.x); pk.s[1] = f2b(v.y); pk.s[2] = f2b(v.z); pk.s[3] = f2b(v.w);
            *(uint2*)&Tb16[rowb + c] = pk.u;
        }
    }
    if (valid && lt == 6 && q == 3) {   // zero the K-pad cols 336..352
        size_t base = (size_t)(b * NN + n) * LP;
        *(uint4*)&Tb16[base + 336] = make_uint4(0, 0, 0, 0);
        *(uint4*)&Tb16[base + 344] = make_uint4(0, 0, 0, 0);
    }
    __syncthreads();
    if (tid < 48) {   // column sums over this block's 64 nodes -> G0 (SUMS, zeroed by prep)
        float s = 0.f;
        #pragma unroll 8
        for (int rr = 0; rr < 64; ++rr) s += Vs[tid][rr];
        unsafeAtomicAdd(&G0[b * LL + l0 + tid], s);
    }
}

// ---------------- loss scratch (aliases the H0 LDS buffer of moe_fused) ----------------
struct LossSM {
    float pc2[BB][EE][2], pn2[BB][EE][2];
    float sc[BB][EE], sn[BB][EE], sy[BB][EE], sg[BB][EE];
    float sti[BB], sto[BB];
    float simp[EE], sload[EE];
};

// full-batch aux loss; 512-thread block-safe.
__device__ void loss_tail(LossSM* S, const float* __restrict__ Gcur,
                          const float* __restrict__ wgL, const float* __restrict__ wnL,
                          const float* __restrict__ noiseL, float* __restrict__ LOSS, int tid)
{
    __syncthreads();
    if (tid < 256) {
        int bb = tid >> 3, ee = (tid >> 1) & 3, sub = tid & 1;
        float c = 0.f, nr = 0.f;
        const float* gp = Gcur + bb * LL;
        for (int l = sub * 168; l < sub * 168 + 168; ++l) {
            float gv = gp[l] * (1.0f / NN);
            c  = fmaf(gv, wgL[l * EE + ee], c);
            nr = fmaf(gv, wnL[l * EE + ee], nr);
        }
        S->pc2[bb][ee][sub] = c; S->pn2[bb][ee][sub] = nr;
    }
    __syncthreads();
    if (tid < 128) {
        int bb = tid >> 2, ee = tid & 3;
        float c  = S->pc2[bb][ee][0] + S->pc2[bb][ee][1];
        float nr = S->pn2[bb][ee][0] + S->pn2[bb][ee][1];
        float ns = softplus_f(nr) + 1e-2f;
        S->sc[bb][ee] = c; S->sn[bb][ee] = ns;
        S->sy[bb][ee] = fmaf(noiseL[bb * EE + ee], ns, c);
    }
    __syncthreads();
    if (tid < 128 && (tid & 3) == 0) {
        int bb = tid >> 2;
        float v[4];
        #pragma unroll
        for (int i = 0; i < 4; ++i) v[i] = S->sy[bb][i];
        int i0 = 0;
        for (int i = 1; i < 4; ++i) if (v[i] > v[i0]) i0 = i;
        int i1 = -1;
        for (int i = 0; i < 4; ++i) { if (i == i0) continue; if (i1 < 0 || v[i] > v[i1]) i1 = i; }
        float m3 = -1e30f;
        for (int i = 0; i < 4; ++i) { if (i == i0 || i == i1) continue; if (v[i] > m3) m3 = v[i]; }
        float e1 = expf(v[i1] - v[i0]);
        float invd = 1.0f / (1.0f + e1);
        #pragma unroll
        for (int i = 0; i < 4; ++i) S->sg[bb][i] = 0.f;
        S->sg[bb][i0] = invd;
        S->sg[bb][i1] = e1 * invd;
        S->sti[bb] = m3;       // (k+1)-th value
        S->sto[bb] = v[i1];    // k-th value
    }
    __syncthreads();
    if (tid < EE) {
        int ee = tid;
        float imp = 0.f, ld = 0.f;
        for (int bb2 = 0; bb2 < BB; ++bb2) {
            imp += S->sg[bb2][ee];
            float thr = (S->sy[bb2][ee] > S->sti[bb2]) ? S->sti[bb2] : S->sto[bb2];
            float z = (S->sc[bb2][ee] - thr) / S->sn[bb2][ee];
            ld += 0.5f * (1.0f + erff(z * 0.7071067811865476f));
        }
        S->simp[ee] = imp; S->sload[ee] = ld;
    }
    __syncthreads();
    if (tid == 0) {
        float aux = 0.f;
        {
            float m = (S->simp[0] + S->simp[1] + S->simp[2] + S->simp[3]) * 0.25f;
            float var = 0.f;
            for (int i = 0; i < 4; ++i) { float d = S->simp[i] - m; var += d * d; }
            var *= (1.0f / 3.0f);
            aux += var / (m * m + 1e-10f);
        }
        {
            float m = (S->sload[0] + S->sload[1] + S->sload[2] + S->sload[3]) * 0.25f;
            float var = 0.f;
            for (int i = 0; i < 4; ++i) { float d = S->sload[i] - m; var += d * d; }
            var *= (1.0f / 3.0f);
            aux += var / (m * m + 1e-10f);
        }
        LOSS[0] += 0.01f * aux;
    }
}

// ---------------- fused MoE layer v3: 16-row tiles, H dbuf, parallel gating ----------------
// grid 672 = 32 b x 21 m-tiles (16 rows each), 512 threads (8 waves), 3 blocks/CU.
// Phases: {stage A + gate partials} bar {fc1-s0->H0} bar {fc2-s0(H0); fc1-s1->H1} bar {fc2-s1(H1)}
// then epilogue: T RMW residual, bf16 mirror, next-layer gate column sums.
__global__ __launch_bounds__(512, 6) void moe_fused(
    short* __restrict__ Tb16, const short* __restrict__ W1t_l,
    const short* __restrict__ W2t_l, const float* __restrict__ b1_l,
    const float* __restrict__ b2_l, float* __restrict__ T,
    const float* __restrict__ Gcur, float* __restrict__ Gnext, float* __restrict__ Gzero,
    const float* __restrict__ wgL, const float* __restrict__ wnL,
    const float* __restrict__ noiseL, float* __restrict__ LOSS, int lastL)
{
    int bid = blockIdx.x;
    int b = bid & 31, y = bid >> 5;   // consecutive bids vary b -> same-b tiles on same XCD
    int m0 = y * 16;
    int tid = threadIdx.x;
    int wave = tid >> 6, lane = tid & 63, quad = lane >> 4, l16 = lane & 15;

    __shared__ short Al[16][360];                 // A tile (11.5 KB)
    __shared__ __align__(16) short H0[16][520];   // H dbuf (16.6 KB each)
    __shared__ __align__(16) short H1[16][520];
    __shared__ float redc[8][4], redn[8][4];

    // zero next-next layer's gate accumulator (only needed at layer 0)
    if (Gzero != nullptr && y == 0 && tid < LL) Gzero[b * LL + tid] = 0.0f;

    // stage A tile: 16 x 352 shorts = 704 uint4
    #pragma unroll
    for (int i = 0; i < 2; ++i) {
        int idx = tid + i * 512;
        if (idx < 704) {
            int r = idx / 44, c = (idx - r * 44) * 8;
            *(uint4*)&Al[r][c] = *(const uint4*)(Tb16 + ((size_t)(b * NN + m0 + r)) * LP + c);
        }
    }
    // gating partials: one thread per time-step (t < 336)
    {
        float pce[4] = {0.f,0.f,0.f,0.f}, pne[4] = {0.f,0.f,0.f,0.f};
        if (tid < LL) {
            float gv = Gcur[b * LL + tid] * (1.0f / NN);
            #pragma unroll
            for (int e2 = 0; e2 < 4; ++e2) {
                pce[e2] = gv * wgL[tid * EE + e2];
                pne[e2] = gv * wnL[tid * EE + e2];
            }
        }
        #pragma unroll
        for (int off = 32; off >= 1; off >>= 1) {
            #pragma unroll
            for (int e2 = 0; e2 < 4; ++e2) {
                pce[e2] += __shfl_xor(pce[e2], off);
                pne[e2] += __shfl_xor(pne[e2], off);
            }
        }
        if (lane == 0) {
            #pragma unroll
            for (int e2 = 0; e2 < 4; ++e2) { redc[wave][e2] = pce[e2]; redn[wave][e2] = pne[e2]; }
        }
    }
    __syncthreads();

    // every thread finalizes gating redundantly (deterministic -> uniform)
    int eA, eB; float gtA, gtB;
    {
        float vv[4];
        #pragma unroll
        for (int e2 = 0; e2 < 4; ++e2) {
            float c = 0.f, nr = 0.f;
            #pragma unroll
            for (int w = 0; w < 8; ++w) { c += redc[w][e2]; nr += redn[w][e2]; }
            float ns = softplus_f(nr) + 1e-2f;
            vv[e2] = fmaf(noiseL[b * EE + e2], ns, c);
        }
        int i0 = 0;
        #pragma unroll
        for (int e2 = 1; e2 < 4; ++e2) if (vv[e2] > vv[i0]) i0 = e2;
        int i1 = -1;
        #pragma unroll
        for (int e2 = 0; e2 < 4; ++e2) { if (e2 == i0) continue; if (i1 < 0 || vv[e2] > vv[i1]) i1 = e2; }
        float e1v = expf(vv[i1] - vv[i0]);
        float invd = 1.0f / (1.0f + e1v);
        eA = i0; eB = i1; gtA = invd; gtB = e1v * invd;
    }

    float4v zero4 = {0.f, 0.f, 0.f, 0.f};
    float4v acc2[3];
    acc2[0] = zero4; acc2[1] = zero4; acc2[2] = zero4;
    int nj = (wave < 5) ? 3 : 2;   // fc2 n-frags per wave: 5*3 + 3*2 = 21 = 336/16

    auto fc1 = [&](int e, float gt, short (*H)[520]) {
        float4v acc1[4];
        #pragma unroll
        for (int j = 0; j < 4; ++j) acc1[j] = zero4;
        const short* Bb1 = W1t_l + ((size_t)(e * DHID + wave * 64 + l16)) * LP + quad * 8;
        #pragma unroll
        for (int ks = 0; ks < 11; ++ks) {
            int off = ks * 32;
            short8 bf[4];
            #pragma unroll
            for (int ni = 0; ni < 4; ++ni) bf[ni] = *(const short8*)(Bb1 + (size_t)(ni * 16) * LP + off);
            short8 af = *(const short8*)&Al[l16][off + quad * 8];
            #pragma unroll
            for (int ni = 0; ni < 4; ++ni)
                acc1[ni] = __builtin_amdgcn_mfma_f32_16x16x32_bf16(af, bf[ni], acc1[ni], 0, 0, 0);
        }
        const float* bb1 = b1_l + (size_t)e * DHID;
        #pragma unroll
        for (int ni = 0; ni < 4; ++ni) {
            int col = wave * 64 + ni * 16 + l16;
            float bias = bb1[col];
            #pragma unroll
            for (int r = 0; r < 4; ++r)
                H[quad * 4 + r][col] = f2b(gt * gelu_f(acc1[ni][r] + bias));
        }
    };
    auto fc2 = [&](int e, const short (*H)[520]) {
        const short* Bb2 = W2t_l + ((size_t)(e * LL + wave * 16 + l16)) * DHID + quad * 8;
        #pragma unroll 4
        for (int ks = 0; ks < 16; ++ks) {
            int off = ks * 32;
            short8 af2 = *(const short8*)&H[l16][off + quad * 8];
            #pragma unroll
            for (int j = 0; j < 3; ++j) {
                if (j < nj) {
                    short8 bf2 = *(const short8*)(Bb2 + (size_t)(j * 128) * DHID + off);
                    acc2[j] = __builtin_amdgcn_mfma_f32_16x16x32_bf16(af2, bf2, acc2[j], 0, 0, 0);
                }
            }
        }
    };

    fc1(eA, gtA, H0);
    __syncthreads();
    fc2(eA, H0);          // reads H0
    fc1(eB, gtB, H1);     // writes H1 (no barrier needed: different buffer)
    __syncthreads();
    fc2(eB, H1);

    // ---- epilogue: residual + bias, single-writer T + bf16 mirror + G partial sums ----
    const float* b2eA = b2_l + (size_t)eA * LL;
    const float* b2eB = b2_l + (size_t)eB * LL;
    float* Tb = T + (size_t)b * NN * LL;
    short* Bt = Tb16 + (size_t)b * NN * LP;
    #pragma unroll
    for (int j = 0; j < 3; ++j) {
        if (j >= nj) continue;
        int gl = wave * 16 + j * 128 + l16;
        float bias2 = gtA * b2eA[gl] + gtB * b2eB[gl];
        float s = 0.f;
        #pragma unroll
        for (int r = 0; r < 4; ++r) {
            int gm = m0 + quad * 4 + r;   // C/D: col=lane&15, row=quad*4+reg
            if (gm < NN) {
                float vv = acc2[j][r] + bias2 + Tb[(size_t)gm * LL + gl];
                if (!lastL) Tb[(size_t)gm * LL + gl] = vv;
                Bt[(size_t)gm * LP + gl] = f2b(vv);
                s += vv;
            }
        }
        s += __shfl_xor(s, 16);
        s += __shfl_xor(s, 32);
        if (!lastL && quad == 0)
            unsafeAtomicAdd(&Gnext[b * LL + gl], s);
    }

    if (bid == 0)
        loss_tail((LossSM*)&H0[0][0], Gcur, wgL, wnL, noiseL, LOSS, tid);
}

// ---------------- projection head: 32-row tiles, 2 barriers, direct-global weights ----------------
__global__ __launch_bounds__(256) void proj_fused(
    const short* __restrict__ Tb16,
    const short* __restrict__ p1wb, const float* __restrict__ p1b,
    const short* __restrict__ p2wb, const float* __restrict__ p2b,
    float* __restrict__ out, const float* __restrict__ LOSS)
{
    __shared__ short Al[32][360];   // 32 x 352 A-tile (stride 360 -> ~2-way banks)
    __shared__ short Hp[32][104];   // 32 x 96 tanh-hidden (stride 104 -> 2-way)
    int m0 = blockIdx.x * 32;
    int tid = threadIdx.x;
    if (blockIdx.x == 0 && tid == 0) out[BPN] = LOSS[0];
    int wave = tid >> 6, lane = tid & 63, quad = lane >> 4, l16 = lane & 15;
    float4v zero4 = {0.f, 0.f, 0.f, 0.f};

    // stage A once: 1408 uint4 (32*352*2B)
    #pragma unroll
    for (int i = 0; i < 6; ++i) {
        int idx = tid + i * 256;
        if (idx < 1408) {
            int r = idx / 44, c = (idx - r * 44) * 8;
            *(uint4*)&Al[r][c] = *(const uint4*)(Tb16 + (size_t)(m0 + r) * LP + c);
        }
    }
    __syncthreads();

    // ---- phase 1: Hp = tanh(A @ p1w^T + p1b). wave: rf = wave&1, cf = (wave>>1)+2j ----
    {
        int rf = wave & 1, cfb = wave >> 1;
        float4v acc1[3];
        #pragma unroll
        for (int j = 0; j < 3; ++j) acc1[j] = zero4;
        const short* B1p0 = p1wb + (size_t)(cfb * 16 + l16) * LP + quad * 8;
        #pragma unroll
        for (int ks = 0; ks < 11; ++ks) {   // barrier-free; B direct-global (L1/L2-served)
            int off = ks * 32;
            short8 af = *(const short8*)&Al[rf * 16 + l16][off + quad * 8];
            #pragma unroll
            for (int j = 0; j < 3; ++j) {
                short8 bf = *(const short8*)(B1p0 + (size_t)j * 32 * LP + off);
                acc1[j] = __builtin_amdgcn_mfma_f32_16x16x32_bf16(af, bf, acc1[j], 0, 0, 0);
            }
        }
        #pragma unroll
        for (int j = 0; j < 3; ++j) {
            int p = (cfb + 2 * j) * 16 + l16;
            float pb = p1b[p];
            #pragma unroll
            for (int r = 0; r < 4; ++r)
                Hp[rf * 16 + quad * 4 + r][p] = f2b(fast_tanh(acc1[j][r] + pb));
        }
    }
    __syncthreads();

    // ---- phase 2 (transposed): c-rows = wave*3+mi frags, node cols; B direct-global ----
    float4v acc2[3][2];
    #pragma unroll
    for (int a = 0; a < 3; ++a)
        #pragma unroll
        for (int j = 0; j < 2; ++j) acc2[a][j] = zero4;
    #pragma unroll
    for (int kc = 0; kc < 3; ++kc) {
        int off = kc * 32 + quad * 8;
        short8 bfv0 = *(const short8*)&Hp[l16][off];
        short8 bfv1 = *(const short8*)&Hp[16 + l16][off];
        #pragma unroll
        for (int mi = 0; mi < 3; ++mi) {
            int cf = wave * 3 + mi;
            short8 af = *(const short8*)(p2wb + (size_t)(cf * 16 + l16) * PP + off);
            acc2[mi][0] = __builtin_amdgcn_mfma_f32_16x16x32_bf16(af, bfv0, acc2[mi][0], 0, 0, 0);
            acc2[mi][1] = __builtin_amdgcn_mfma_f32_16x16x32_bf16(af, bfv1, acc2[mi][1], 0, 0, 0);
        }
    }
    // stores: lane l16 -> consecutive node (64B runs per quad); 321*32 = MROWS exactly
    int bqv[2], ndv[2];
    #pragma unroll
    for (int ni = 0; ni < 2; ++ni) {
        int gm = m0 + ni * 16 + l16;
        int bq = gm / NN;
        bqv[ni] = bq; ndv[ni] = gm - bq * NN;
    }
    #pragma unroll
    for (int mi = 0; mi < 3; ++mi) {
        #pragma unroll
        for (int r = 0; r < 4; ++r) {
            int c = (wave * 3 + mi) * 16 + quad * 4 + r;
            float pb = p2b[c];
            int p = c >> 1;
            if ((r & 1) == 0) {               // c even -> mean
                #pragma unroll
                for (int ni = 0; ni < 2; ++ni) {
                    float v = acc2[mi][ni][r] + pb;
                    out[((size_t)bqv[ni] * PP + p) * NN + ndv[ni]] = v;
                }
            } else {                          // c odd -> std
                #pragma unroll
                for (int ni = 0; ni < 2; ++ni) {
                    float v = acc2[mi][ni][r] + pb;
                    out[BPN + 1 + ((size_t)bqv[ni] * PP + p) * NN + ndv[ni]] = softplus_f(v) + 1e-6f;
                }
            }
        }
    }
}

extern "C" void kernel_launch(void* const* d_in, const int* in_sizes, int n_in,
                              void* d_out, int out_size, void* d_ws, size_t ws_size,
                              hipStream_t stream)
{
    const float* x     = (const float*)d_in[0];
    const float* noise = (const float*)d_in[1];
    const float* wg    = (const float*)d_in[2];
    const float* wn    = (const float*)d_in[3];
    const float* W1    = (const float*)d_in[4];
    const float* b1    = (const float*)d_in[5];
    const float* W2    = (const float*)d_in[6];
    const float* b2    = (const float*)d_in[7];
    const float* p1w   = (const float*)d_in[8];
    const float* p1b   = (const float*)d_in[9];
    const float* p2w   = (const float*)d_in[10];
    const float* p2b   = (const float*)d_in[11];
    float* out = (float*)d_out;

    float* ws   = (float*)d_ws;
    float* T    = ws;                          // STOT fp32 (stride LL)
    float* G0   = T + STOT;                    // BB*LL gate sums (3-buffer rotation)
    float* G1   = G0 + BB * LL;
    float* G2   = G1 + BB * LL;
    float* LOSS = G2 + BB * LL;                // 8
    float* MU   = LOSS + 8;                    // BB*NN
    float* IV   = MU + MROWS;                  // BB*NN
    short* W1t  = (short*)(IV + MROWS);        // NLAYERS*EE*DHID*LP bf16 [le][d][k]
    short* W2t  = W1t + (size_t)NLAYERS * EE * DHID * LP;  // NLAYERS*EE*LL*DHID
    short* p1wb = W2t + (size_t)NLAYERS * EE * LL * DHID;  // 96*LP (K-padded)
    short* p2wb = p1wb + PP * LP;              // 192*96
    short* Tb16 = p2wb + 2 * PP * PP;          // (MROWS+64) x LP bf16 mirror of T

    prep_kernel<<<1549, 256, 0, stream>>>(x, W1, W2, p1w, p2w, MU, IV, LOSS, G0, G1,
                                          W1t, W2t, p1wb, p2wb);
    revin_tn<<<dim3(BB, 6, 7), 256, 0, stream>>>(x, MU, IV, T, Tb16, G0);

    for (int l = 0; l < NLAYERS; ++l) {
        const float* Gcur = (l == 0) ? G0 : (l == 1) ? G1 : G2;
        float* Gnext      = (l == 0) ? G1 : (l == 1) ? G2 : G0;   // unused when lastL
        float* Gzero      = (l == 0) ? G2 : nullptr;
        moe_fused<<<672, 512, 0, stream>>>(
            Tb16, W1t + (size_t)l * EE * DHID * LP, W2t + (size_t)l * EE * LL * DHID,
            b1 + (size_t)l * EE * DHID, b2 + (size_t)l * EE * LL, T,
            Gcur, Gnext, Gzero,
            wg + (size_t)l * LL * EE, wn + (size_t)l * LL * EE,
            noise + (size_t)l * BB * EE, LOSS, (l == NLAYERS - 1) ? 1 : 0);
    }
    proj_fused<<<321, 256, 0, stream>>>(Tb16, p1wb, p1b, p2wb, p2b, out, LOSS);
}

// Round 4
// 347.084 us; speedup vs baseline: 1.4643x; 1.4643x over previous
//
#include <hip/hip_runtime.h>
#include <hip/hip_bf16.h>

#define NLAYERS 3
#define BB 32
#define LL 336
#define LP 352                 // K-padded stride for Tb16 / p1wb (zeros in pad)
#define NN 321
#define EE 4
#define DHID 512
#define PP 96
#define STOT (BB*NN*LL)        // 3451392
#define MROWS (BB*NN)          // 10272
#define BPN ((size_t)BB*PP*NN) // 986112

// fragment-contiguous weight layouts:
// W1f[e][nf=32][ks=11][lane=64][8]  (frag stride 5632, e stride 180224)
// W2f[e][nf=21][ks=16][lane=64][8]  (frag stride 8192, e stride 172032)
#define F1S 5632
#define E1S 180224
#define F2S 8192
#define E2S 172032

typedef __attribute__((ext_vector_type(8))) short short8;
typedef __attribute__((ext_vector_type(4))) float float4v;

union BF { __hip_bfloat16 h; short s; };

__device__ __forceinline__ short f2b(float f) { BF u; u.h = __float2bfloat16(f); return u.s; }

__device__ __forceinline__ float fast_tanh(float y) {
    float e = __expf(2.0f * y);
    return 1.0f - 2.0f / (e + 1.0f);   // exact limits at +-inf
}
__device__ __forceinline__ float gelu_f(float x) {
    return 0.5f * x * (1.0f + fast_tanh(0.7978845608028654f * (x + 0.044715f * x * x * x)));
}
__device__ __forceinline__ float softplus_f(float x) {
    return fmaxf(x, 0.0f) + log1pf(expf(-fabsf(x)));
}

// ---------------- prep: weight transpose->fragment layout + pcvt + RevIN stats + zeroing ----------------
// flat grid 1549: [0,576) W1->W1f, [576,1152) W2->W2f, [1152,1344) revin_stats(+zero G0/LOSS),
// [1344,1549) pcvt.
__global__ __launch_bounds__(256) void prep_kernel(
    const float* __restrict__ x, const float* __restrict__ W1, const float* __restrict__ W2,
    const float* __restrict__ p1w, const float* __restrict__ p2w,
    float* __restrict__ MU, float* __restrict__ IV, float* __restrict__ LOSS,
    float* __restrict__ G0, short* __restrict__ W1f, short* __restrict__ W2f,
    short* __restrict__ p1wb, short* __restrict__ p2wb)
{
    __shared__ short Ws[64][72];
    __shared__ float Ss[4][64], Sq[4][64];
    int idx = blockIdx.x, tid = threadIdx.x;
    if (idx < 1152) {
        const float* src; int K, D, KS, bx, by, le;
        if (idx < 576) {
            le = idx / 48; int r = idx % 48;
            src = W1 + (size_t)le * LL * DHID;
            K = LL; D = DHID; KS = LP; bx = r % 8; by = r / 8;
        } else {
            int s2 = idx - 576; le = s2 / 48; int r = s2 % 48;
            src = W2 + (size_t)le * DHID * LL;
            K = DHID; D = LL; KS = DHID; bx = r % 6; by = r / 6;
        }
        int d0 = bx * 64, k0 = by * 64;
        #pragma unroll
        for (int i = 0; i < 16; ++i) {
            int lin = tid + i * 256;
            int ki = lin >> 6, dj = lin & 63;
            int k = k0 + ki, d = d0 + dj;
            Ws[ki][dj] = (k < K && d < D) ? f2b(src[(size_t)k * D + d]) : (short)0;
        }
        __syncthreads();
        int di = tid >> 2, d = d0 + di;
        if (d >= D) return;
        #pragma unroll
        for (int kp = 0; kp < 2; ++kp) {
            int kj = ((tid & 3) + 4 * kp) * 8;
            int k = k0 + kj;
            if (k >= KS) continue;
            union { short s[8]; uint4 u; } pk;
            #pragma unroll
            for (int j = 0; j < 8; ++j) pk.s[j] = Ws[kj + j][di];
            int nf = d >> 4;
            int ks = k >> 5;
            int l  = (((k >> 3) & 3) << 4) | (d & 15);
            if (idx < 576) {   // W1f: [le][nf][ks(11)][l][8]
                size_t o = (size_t)le * E1S + ((size_t)(nf * 11 + ks) * 64 + l) * 8;
                *(uint4*)&W1f[o] = pk.u;
            } else {           // W2f: [le][nf][ks(16)][l][8]
                size_t o = (size_t)le * E2S + ((size_t)(nf * 16 + ks) * 64 + l) * 8;
                *(uint4*)&W2f[o] = pk.u;
            }
        }
    } else if (idx < 1344) {
        int q = idx - 1152;
        int b = q / 6, nt = q % 6;
        if (tid < 56) G0[q * 56 + tid] = 0.0f;      // 192*56 = BB*LL exactly
        if (q == 0 && tid < 8) LOSS[tid] = 0.0f;
        int ni = tid & 63, lc = tid >> 6;
        int n = nt * 64 + ni;
        float s = 0.f, ss = 0.f;
        if (n < NN) {
            const float* xp = x + ((size_t)b * LL + lc * 84) * NN + n;
            for (int l = 0; l < 84; ++l, xp += NN) {
                float v = *xp; s += v; ss = fmaf(v, v, ss);
            }
        }
        Ss[lc][ni] = s; Sq[lc][ni] = ss;
        __syncthreads();
        if (lc == 0 && n < NN) {
            float st = ((Ss[0][ni] + Ss[1][ni]) + Ss[2][ni]) + Ss[3][ni];
            float sq = ((Sq[0][ni] + Sq[1][ni]) + Sq[2][ni]) + Sq[3][ni];
            float mu  = st * (1.0f / LL);
            float var = sq * (1.0f / LL) - mu * mu;   // ddof=0
            MU[b * NN + n] = mu;
            IV[b * NN + n] = 1.0f / sqrtf(var + 1e-5f);
        }
    } else {
        int i = (idx - 1344) * 256 + tid;
        if (i < PP * LP) {
            int n = i / LP, k = i - n * LP;
            p1wb[i] = (k < LL) ? f2b(p1w[n * LL + k]) : (short)0;
        } else if (i < PP * LP + 2 * PP * PP) {
            int j = i - PP * LP;
            p2wb[j] = f2b(p2w[j]);
        }
    }
}

// ---------------- RevIN transpose+normalize + layer-0 gate-sum accumulation ----------------
__global__ __launch_bounds__(256) void revin_tn(
    const float* __restrict__ x, const float* __restrict__ MU, const float* __restrict__ IV,
    float* __restrict__ T, short* __restrict__ Tb16, float* __restrict__ G0)
{
    int b = blockIdx.x, nt = blockIdx.y, lt = blockIdx.z;
    int n0 = nt * 64, l0 = lt * 48;
    __shared__ float Ls[48][65];
    __shared__ float Vs[48][65];
    int tid = threadIdx.x;
    #pragma unroll
    for (int i = 0; i < 12; ++i) {
        int lin = tid + i * 256;
        int li = lin >> 6, ni = lin & 63;
        int n = n0 + ni;
        Ls[li][ni] = (n < NN) ? x[((size_t)b * LL + l0 + li) * NN + n] : 0.f;
    }
    __syncthreads();
    int r = tid >> 2, q = tid & 3;
    int n = n0 + r;
    bool valid = (n < NN);
    float mu = 0.f, iv = 0.f;
    if (valid) { mu = MU[b * NN + n]; iv = IV[b * NN + n]; }
    size_t rowf = (size_t)(b * NN + (valid ? n : 0)) * LL + l0;
    size_t rowb = (size_t)(b * NN + (valid ? n : 0)) * LP + l0;
    #pragma unroll
    for (int k = 0; k < 3; ++k) {
        int c = (q + 4 * k) * 4;
        float4 v;
        v.x = (Ls[c    ][r] - mu) * iv;
        v.y = (Ls[c + 1][r] - mu) * iv;
        v.z = (Ls[c + 2][r] - mu) * iv;
        v.w = (Ls[c + 3][r] - mu) * iv;
        Vs[c][r] = v.x; Vs[c + 1][r] = v.y; Vs[c + 2][r] = v.z; Vs[c + 3][r] = v.w;
        if (valid) {
            *(float4*)&T[rowf + c] = v;
            union { short s[4]; uint2 u; } pk;
            pk.s[0] = f2b(v.x); pk.s[1] = f2b(v.y); pk.s[2] = f2b(v.z); pk.s[3] = f2b(v.w);
            *(uint2*)&Tb16[rowb + c] = pk.u;
        }
    }
    if (valid && lt == 6 && q == 3) {   // zero the K-pad cols 336..352
        size_t base = (size_t)(b * NN + n) * LP;
        *(uint4*)&Tb16[base + 336] = make_uint4(0, 0, 0, 0);
        *(uint4*)&Tb16[base + 344] = make_uint4(0, 0, 0, 0);
    }
    __syncthreads();
    if (tid < 48) {   // column sums over this block's 64 nodes -> G0 (SUMS, zeroed by prep)
        float s = 0.f;
        #pragma unroll 8
        for (int rr = 0; rr < 64; ++rr) s += Vs[tid][rr];
        unsafeAtomicAdd(&G0[b * LL + l0 + tid], s);
    }
}

// ---------------- loss scratch (aliases fc1's A-tile LDS) ----------------
struct LossSM {
    float pc2[BB][EE][2], pn2[BB][EE][2];
    float sc[BB][EE], sn[BB][EE], sy[BB][EE], sg[BB][EE];
    float sti[BB], sto[BB];
    float simp[EE], sload[EE];
};

// full-batch aux loss + zero Gnext; 256-thread block. Leading barrier protects the alias.
__device__ void loss_tail(LossSM* S, const float* __restrict__ Gcur, float* __restrict__ Gnext,
                          const float* __restrict__ wgL, const float* __restrict__ wnL,
                          const float* __restrict__ noiseL, float* __restrict__ LOSS, int tid)
{
    __syncthreads();
    for (int t = tid; t < BB * LL; t += 256) Gnext[t] = 0.0f;
    {
        int bb = tid >> 3, ee = (tid >> 1) & 3, sub = tid & 1;
        float c = 0.f, nr = 0.f;
        const float* gp = Gcur + bb * LL;
        for (int l = sub * 168; l < sub * 168 + 168; ++l) {
            float gv = gp[l] * (1.0f / NN);
            c  = fmaf(gv, wgL[l * EE + ee], c);
            nr = fmaf(gv, wnL[l * EE + ee], nr);
        }
        S->pc2[bb][ee][sub] = c; S->pn2[bb][ee][sub] = nr;
    }
    __syncthreads();
    if (tid < 128) {
        int bb = tid >> 2, ee = tid & 3;
        float c  = S->pc2[bb][ee][0] + S->pc2[bb][ee][1];
        float nr = S->pn2[bb][ee][0] + S->pn2[bb][ee][1];
        float ns = softplus_f(nr) + 1e-2f;
        S->sc[bb][ee] = c; S->sn[bb][ee] = ns;
        S->sy[bb][ee] = fmaf(noiseL[bb * EE + ee], ns, c);
    }
    __syncthreads();
    if (tid < 128 && (tid & 3) == 0) {
        int bb = tid >> 2;
        float v[4];
        #pragma unroll
        for (int i = 0; i < 4; ++i) v[i] = S->sy[bb][i];
        int i0 = 0;
        for (int i = 1; i < 4; ++i) if (v[i] > v[i0]) i0 = i;
        int i1 = -1;
        for (int i = 0; i < 4; ++i) { if (i == i0) continue; if (i1 < 0 || v[i] > v[i1]) i1 = i; }
        float m3 = -1e30f;
        for (int i = 0; i < 4; ++i) { if (i == i0 || i == i1) continue; if (v[i] > m3) m3 = v[i]; }
        float e1 = expf(v[i1] - v[i0]);
        float invd = 1.0f / (1.0f + e1);
        #pragma unroll
        for (int i = 0; i < 4; ++i) S->sg[bb][i] = 0.f;
        S->sg[bb][i0] = invd;
        S->sg[bb][i1] = e1 * invd;
        S->sti[bb] = m3;       // (k+1)-th value
        S->sto[bb] = v[i1];    // k-th value
    }
    __syncthreads();
    if (tid < EE) {
        int ee = tid;
        float imp = 0.f, ld = 0.f;
        for (int bb2 = 0; bb2 < BB; ++bb2) {
            imp += S->sg[bb2][ee];
            float thr = (S->sy[bb2][ee] > S->sti[bb2]) ? S->sti[bb2] : S->sto[bb2];
            float z = (S->sc[bb2][ee] - thr) / S->sn[bb2][ee];
            ld += 0.5f * (1.0f + erff(z * 0.7071067811865476f));
        }
        S->simp[ee] = imp; S->sload[ee] = ld;
    }
    __syncthreads();
    if (tid == 0) {
        float aux = 0.f;
        {
            float m = (S->simp[0] + S->simp[1] + S->simp[2] + S->simp[3]) * 0.25f;
            float var = 0.f;
            for (int i = 0; i < 4; ++i) { float d = S->simp[i] - m; var += d * d; }
            var *= (1.0f / 3.0f);
            aux += var / (m * m + 1e-10f);
        }
        {
            float m = (S->sload[0] + S->sload[1] + S->sload[2] + S->sload[3]) * 0.25f;
            float var = 0.f;
            for (int i = 0; i < 4; ++i) { float d = S->sload[i] - m; var += d * d; }
            var *= (1.0f / 3.0f);
            aux += var / (m * m + 1e-10f);
        }
        LOSS[0] += 0.01f * aux;
    }
}

// ---------------- FC1 (MFMA) + inline per-b gating; frag-contiguous B; prefetch ----------------
// flat grid 768 = 4 v x 6 y x 32 b (XCD-swizzled). v = (slot<<1)|xt, n0 = xt*256, acc 4x4.
__global__ __launch_bounds__(256, 3) void fc1_mfma(
    const short* __restrict__ Tb16, const short* __restrict__ W1f_l,
    const float* __restrict__ b1_l,
    const float* __restrict__ Gcur, float* __restrict__ Gnext,
    const float* __restrict__ wgL, const float* __restrict__ wnL,
    const float* __restrict__ noiseL,
    int* __restrict__ IDX, float* __restrict__ GV,
    short* __restrict__ Hs, float* __restrict__ LOSS)
{
    int i = blockIdx.x;
    int low = i & 7, rest = i >> 3;
    int v = rest & 3, ghi = rest >> 2;       // v in [0,4), ghi in [0,24)
    int g = ghi * 8 + low;                   // [0,192)
    int y = g % 6, b = g / 6;
    int xt = v & 1, slot = v >> 1;
    int m0 = y * 64, n0 = xt * 256;
    int tid = threadIdx.x;
    int wave = tid >> 6, lane = tid & 63, quad = lane >> 4, l16 = lane & 15;
    __shared__ __align__(16) short Al[64][360];   // stride 720B -> ~2-way banks
    __shared__ int sE[2];
    __shared__ float sGt[2];
    {   // stage full 64 x 352 A tile once
        int r = tid >> 2, c0 = (tid & 3) * 8;
        const short* src = Tb16 + ((size_t)b * NN + m0 + r) * LP + c0;
        #pragma unroll
        for (int ks = 0; ks < 11; ++ks)
            *(uint4*)&Al[r][c0 + ks * 32] = *(const uint4*)(src + ks * 32);
    }
    // wave 0: this block's b gating (overlapped with staging of other waves)
    if (tid < 64) {
        float pc[4] = {0.f,0.f,0.f,0.f}, pn[4] = {0.f,0.f,0.f,0.f};
        const float* gp = Gcur + b * LL;
        for (int l = tid; l < LL; l += 64) {
            float gv = gp[l] * (1.0f / NN);
            #pragma unroll
            for (int e2 = 0; e2 < 4; ++e2) {
                pc[e2] = fmaf(gv, wgL[l * EE + e2], pc[e2]);
                pn[e2] = fmaf(gv, wnL[l * EE + e2], pn[e2]);
            }
        }
        #pragma unroll
        for (int off = 32; off >= 1; off >>= 1) {
            #pragma unroll
            for (int e2 = 0; e2 < 4; ++e2) {
                pc[e2] += __shfl_xor(pc[e2], off);
                pn[e2] += __shfl_xor(pn[e2], off);
            }
        }
        if (tid == 0) {
            float vv[4];
            #pragma unroll
            for (int e2 = 0; e2 < 4; ++e2) {
                float ns = softplus_f(pn[e2]) + 1e-2f;
                vv[e2] = fmaf(noiseL[b * EE + e2], ns, pc[e2]);
            }
            int i0 = 0;
            for (int e2 = 1; e2 < 4; ++e2) if (vv[e2] > vv[i0]) i0 = e2;
            int i1 = -1;
            for (int e2 = 0; e2 < 4; ++e2) { if (e2 == i0) continue; if (i1 < 0 || vv[e2] > vv[i1]) i1 = e2; }
            float e1v = expf(vv[i1] - vv[i0]);
            float invd = 1.0f / (1.0f + e1v);
            sE[0] = i0; sE[1] = i1; sGt[0] = invd; sGt[1] = e1v * invd;
        }
    }
    __syncthreads();
    int e = sE[slot];
    float gt = sGt[slot];
    if (y == 0 && v == 0 && tid < 2) {   // publish for fc2 (one block per b)
        IDX[2 * b + tid] = sE[tid];
        GV[2 * b + tid] = sGt[tid];
    }

    // B fragments: wave-contiguous 1KB reads. nf = xt*16 + wave*4 + ni
    const short* Bf = W1f_l + (size_t)(e * 32 + xt * 16 + wave * 4) * F1S + lane * 8;
    float4v zero4 = {0.f, 0.f, 0.f, 0.f};
    float4v acc[4][4];
    #pragma unroll
    for (int a = 0; a < 4; ++a)
        #pragma unroll
        for (int j = 0; j < 4; ++j) acc[a][j] = zero4;

    short8 bc0 = *(const short8*)(Bf);
    short8 bc1 = *(const short8*)(Bf + F1S);
    short8 bc2 = *(const short8*)(Bf + 2 * F1S);
    short8 bc3 = *(const short8*)(Bf + 3 * F1S);
    #pragma unroll
    for (int ks = 0; ks < 11; ++ks) {
        short8 bn0, bn1, bn2, bn3;
        if (ks < 10) {
            int o = (ks + 1) * 512;
            bn0 = *(const short8*)(Bf + o);
            bn1 = *(const short8*)(Bf + F1S + o);
            bn2 = *(const short8*)(Bf + 2 * F1S + o);
            bn3 = *(const short8*)(Bf + 3 * F1S + o);
        }
        int off = ks * 32;
        short8 af[4];
        #pragma unroll
        for (int mi = 0; mi < 4; ++mi) af[mi] = *(const short8*)&Al[mi * 16 + l16][off + quad * 8];
        #pragma unroll
        for (int mi = 0; mi < 4; ++mi) {
            acc[mi][0] = __builtin_amdgcn_mfma_f32_16x16x32_bf16(af[mi], bc0, acc[mi][0], 0, 0, 0);
            acc[mi][1] = __builtin_amdgcn_mfma_f32_16x16x32_bf16(af[mi], bc1, acc[mi][1], 0, 0, 0);
            acc[mi][2] = __builtin_amdgcn_mfma_f32_16x16x32_bf16(af[mi], bc2, acc[mi][2], 0, 0, 0);
            acc[mi][3] = __builtin_amdgcn_mfma_f32_16x16x32_bf16(af[mi], bc3, acc[mi][3], 0, 0, 0);
        }
        if (ks < 10) { bc0 = bn0; bc1 = bn1; bc2 = bn2; bc3 = bn3; }
    }
    const float* bb = b1_l + (size_t)e * DHID;
    int wn4 = wave * 64;
    float bias[4];
    #pragma unroll
    for (int ni = 0; ni < 4; ++ni) bias[ni] = bb[n0 + wn4 + ni * 16 + l16];
    short* Ho = Hs + (size_t)(b * 2 + slot) * NN * DHID;
    #pragma unroll
    for (int mi = 0; mi < 4; ++mi) {
        #pragma unroll
        for (int r = 0; r < 4; ++r) {
            int gm = m0 + mi * 16 + quad * 4 + r;   // C/D: col=lane&15, row=quad*4+reg
            if (gm >= NN) continue;
            #pragma unroll
            for (int ni = 0; ni < 4; ++ni) {
                int gd = n0 + wn4 + ni * 16 + l16;
                float vv = acc[mi][ni][r] + bias[ni];
                Ho[(size_t)gm * DHID + gd] = f2b(gt * gelu_f(vv));
            }
        }
    }
    if (i == 0) loss_tail((LossSM*)&Al[0][0], Gcur, Gnext, wgL, wnL, noiseL, LOSS, tid);
}

// ---------------- FC2 fused: both slots (K=1024), frag-contiguous B, atomic-free T update ----
// flat grid 576 = 3 v x 6 y x 32 b, XCD-swizzled.
__global__ __launch_bounds__(256, 4) void fc2_fused(
    const short* __restrict__ Hs, const short* __restrict__ W2f_l,
    const float* __restrict__ b2_l, float* __restrict__ T,
    short* __restrict__ Tb16, float* __restrict__ Gnext,
    const int* __restrict__ IDX, const float* __restrict__ GV, int lastL)
{
    int i = blockIdx.x;
    int low = i & 7, rest = i >> 3;
    int v = rest % 3, ghi = rest / 3;        // v in [0,3), ghi in [0,24)
    int g = ghi * 8 + low;                   // [0,192)
    int y = g % 6, b = g / 6;
    int m0 = y * 64, n0 = v * 128;
    int tid = threadIdx.x;
    int wave = tid >> 6, lane = tid & 63, quad = lane >> 4, l16 = lane & 15;
    int wn = wave * 32;
    __shared__ short Al[64][264];   // stride 528B -> 2-way frag reads
    int e0 = IDX[2 * b], e1 = IDX[2 * b + 1];
    float gt0 = GV[2 * b], gt1 = GV[2 * b + 1];
    float4v zero4 = {0.f, 0.f, 0.f, 0.f};
    float4v acc[4][2];
    #pragma unroll
    for (int a = 0; a < 4; ++a)
        #pragma unroll
        for (int j = 0; j < 2; ++j) acc[a][j] = zero4;

    int nfr = v * 8 + wave * 2;
    int nf0 = (nfr > 20) ? 20 : nfr;         // clamp: OOB frags loaded but discarded
    int nf1 = (nfr + 1 > 20) ? 20 : nfr + 1;

    int r8 = tid >> 5, c0s = (tid & 31) * 8;
    #pragma unroll
    for (int sc2 = 0; sc2 < 4; ++sc2) {      // phase = (slot, chunk)
        int slot = sc2 >> 1, chunk = sc2 & 1;
        int koff = chunk * 256;
        int ez = slot ? e1 : e0;
        const short* As = Hs + ((size_t)(b * 2 + slot) * NN + m0) * DHID + koff;
        #pragma unroll
        for (int a = 0; a < 8; ++a)
            *(uint4*)&Al[a * 8 + r8][c0s] = *(const uint4*)(As + (size_t)(a * 8 + r8) * DHID + c0s);
        __syncthreads();
        const short* B0 = W2f_l + (size_t)ez * E2S + (size_t)nf0 * F2S + (size_t)chunk * 8 * 512 + lane * 8;
        const short* B1 = W2f_l + (size_t)ez * E2S + (size_t)nf1 * F2S + (size_t)chunk * 8 * 512 + lane * 8;
        short8 c0 = *(const short8*)(B0);
        short8 c1 = *(const short8*)(B1);
        #pragma unroll
        for (int ks = 0; ks < 8; ++ks) {
            short8 n0v, n1v;
            if (ks < 7) {
                n0v = *(const short8*)(B0 + (ks + 1) * 512);
                n1v = *(const short8*)(B1 + (ks + 1) * 512);
            }
            int off = ks * 32;
            short8 af[4];
            #pragma unroll
            for (int mi = 0; mi < 4; ++mi) af[mi] = *(const short8*)&Al[mi * 16 + l16][off + quad * 8];
            #pragma unroll
            for (int mi = 0; mi < 4; ++mi) {
                acc[mi][0] = __builtin_amdgcn_mfma_f32_16x16x32_bf16(af[mi], c0, acc[mi][0], 0, 0, 0);
                acc[mi][1] = __builtin_amdgcn_mfma_f32_16x16x32_bf16(af[mi], c1, acc[mi][1], 0, 0, 0);
            }
            if (ks < 7) { c0 = n0v; c1 = n1v; }
        }
        __syncthreads();
    }
    // epilogue: residual + bias, single-writer T + bf16 mirror + G partial sums
    const float* b2e0 = b2_l + (size_t)e0 * LL;
    const float* b2e1 = b2_l + (size_t)e1 * LL;
    float* Tb = T + (size_t)b * NN * LL;
    short* Bt = Tb16 + (size_t)b * NN * LP;
    #pragma unroll
    for (int ni = 0; ni < 2; ++ni) {
        int gl = n0 + wn + ni * 16 + l16;
        float s = 0.f;
        if (gl < LL) {
            float bias = gt0 * b2e0[gl] + gt1 * b2e1[gl];
            #pragma unroll
            for (int mi = 0; mi < 4; ++mi) {
                #pragma unroll
                for (int r = 0; r < 4; ++r) {
                    int gm = m0 + mi * 16 + quad * 4 + r;
                    if (gm < NN) {
                        float vv = acc[mi][ni][r] + bias + Tb[(size_t)gm * LL + gl];
                        if (!lastL) Tb[(size_t)gm * LL + gl] = vv;
                        Bt[(size_t)gm * LP + gl] = f2b(vv);
                        s += vv;
                    }
                }
            }
        }
        s += __shfl_xor(s, 16);
        s += __shfl_xor(s, 32);
        if (!lastL && quad == 0 && gl < LL)
            unsafeAtomicAdd(&Gnext[b * LL + gl], s);
    }
}

// ---------------- projection head: 32-row tiles, 2 barriers, direct-global weights ----------------
__global__ __launch_bounds__(256) void proj_fused(
    const short* __restrict__ Tb16,
    const short* __restrict__ p1wb, const float* __restrict__ p1b,
    const short* __restrict__ p2wb, const float* __restrict__ p2b,
    float* __restrict__ out, const float* __restrict__ LOSS)
{
    __shared__ short Al[32][360];   // 32 x 352 A-tile (stride 360 -> ~2-way banks)
    __shared__ short Hp[32][104];   // 32 x 96 tanh-hidden (stride 104 -> 2-way)
    int m0 = blockIdx.x * 32;
    int tid = threadIdx.x;
    if (blockIdx.x == 0 && tid == 0) out[BPN] = LOSS[0];
    int wave = tid >> 6, lane = tid & 63, quad = lane >> 4, l16 = lane & 15;
    float4v zero4 = {0.f, 0.f, 0.f, 0.f};

    // stage A once: 1408 uint4 (32*352*2B)
    #pragma unroll
    for (int i = 0; i < 6; ++i) {
        int idx = tid + i * 256;
        if (idx < 1408) {
            int r = idx / 44, c = (idx - r * 44) * 8;
            *(uint4*)&Al[r][c] = *(const uint4*)(Tb16 + (size_t)(m0 + r) * LP + c);
        }
    }
    __syncthreads();

    // ---- phase 1: Hp = tanh(A @ p1w^T + p1b). wave: rf = wave&1, cf = (wave>>1)+2j ----
    {
        int rf = wave & 1, cfb = wave >> 1;
        float4v acc1[3];
        #pragma unroll
        for (int j = 0; j < 3; ++j) acc1[j] = zero4;
        const short* B1p0 = p1wb + (size_t)(cfb * 16 + l16) * LP + quad * 8;
        #pragma unroll
        for (int ks = 0; ks < 11; ++ks) {   // barrier-free; B direct-global (L1/L2-served)
            int off = ks * 32;
            short8 af = *(const short8*)&Al[rf * 16 + l16][off + quad * 8];
            #pragma unroll
            for (int j = 0; j < 3; ++j) {
                short8 bf = *(const short8*)(B1p0 + (size_t)j * 32 * LP + off);
                acc1[j] = __builtin_amdgcn_mfma_f32_16x16x32_bf16(af, bf, acc1[j], 0, 0, 0);
            }
        }
        #pragma unroll
        for (int j = 0; j < 3; ++j) {
            int p = (cfb + 2 * j) * 16 + l16;
            float pb = p1b[p];
            #pragma unroll
            for (int r = 0; r < 4; ++r)
                Hp[rf * 16 + quad * 4 + r][p] = f2b(fast_tanh(acc1[j][r] + pb));
        }
    }
    __syncthreads();

    // ---- phase 2 (transposed): c-rows = wave*3+mi frags, node cols; B direct-global ----
    float4v acc2[3][2];
    #pragma unroll
    for (int a = 0; a < 3; ++a)
        #pragma unroll
        for (int j = 0; j < 2; ++j) acc2[a][j] = zero4;
    #pragma unroll
    for (int kc = 0; kc < 3; ++kc) {
        int off = kc * 32 + quad * 8;
        short8 bfv0 = *(const short8*)&Hp[l16][off];
        short8 bfv1 = *(const short8*)&Hp[16 + l16][off];
        #pragma unroll
        for (int mi = 0; mi < 3; ++mi) {
            int cf = wave * 3 + mi;
            short8 af = *(const short8*)(p2wb + (size_t)(cf * 16 + l16) * PP + off);
            acc2[mi][0] = __builtin_amdgcn_mfma_f32_16x16x32_bf16(af, bfv0, acc2[mi][0], 0, 0, 0);
            acc2[mi][1] = __builtin_amdgcn_mfma_f32_16x16x32_bf16(af, bfv1, acc2[mi][1], 0, 0, 0);
        }
    }
    // stores: lane l16 -> consecutive node (64B runs per quad); 321*32 = MROWS exactly
    int bqv[2], ndv[2];
    #pragma unroll
    for (int ni = 0; ni < 2; ++ni) {
        int gm = m0 + ni * 16 + l16;
        int bq = gm / NN;
        bqv[ni] = bq; ndv[ni] = gm - bq * NN;
    }
    #pragma unroll
    for (int mi = 0; mi < 3; ++mi) {
        #pragma unroll
        for (int r = 0; r < 4; ++r) {
            int c = (wave * 3 + mi) * 16 + quad * 4 + r;
            float pb = p2b[c];
            int p = c >> 1;
            if ((r & 1) == 0) {               // c even -> mean
                #pragma unroll
                for (int ni = 0; ni < 2; ++ni) {
                    float v = acc2[mi][ni][r] + pb;
                    out[((size_t)bqv[ni] * PP + p) * NN + ndv[ni]] = v;
                }
            } else {                          // c odd -> std
                #pragma unroll
                for (int ni = 0; ni < 2; ++ni) {
                    float v = acc2[mi][ni][r] + pb;
                    out[BPN + 1 + ((size_t)bqv[ni] * PP + p) * NN + ndv[ni]] = softplus_f(v) + 1e-6f;
                }
            }
        }
    }
}

extern "C" void kernel_launch(void* const* d_in, const int* in_sizes, int n_in,
                              void* d_out, int out_size, void* d_ws, size_t ws_size,
                              hipStream_t stream)
{
    const float* x     = (const float*)d_in[0];
    const float* noise = (const float*)d_in[1];
    const float* wg    = (const float*)d_in[2];
    const float* wn    = (const float*)d_in[3];
    const float* W1    = (const float*)d_in[4];
    const float* b1    = (const float*)d_in[5];
    const float* W2    = (const float*)d_in[6];
    const float* b2    = (const float*)d_in[7];
    const float* p1w   = (const float*)d_in[8];
    const float* p1b   = (const float*)d_in[9];
    const float* p2w   = (const float*)d_in[10];
    const float* p2b   = (const float*)d_in[11];
    float* out = (float*)d_out;

    float* ws   = (float*)d_ws;
    float* T    = ws;                          // STOT fp32 (stride LL)
    float* G0   = T + STOT;                    // BB*LL gate sums (double rotation)
    float* G1   = G0 + BB * LL;
    float* LOSS = G1 + BB * LL;                // 8
    float* GV   = LOSS + 8;                    // 64
    int*   IDX  = (int*)(GV + 64);             // 64
    float* MU   = (float*)(IDX + 64);          // BB*NN
    float* IV   = MU + MROWS;                  // BB*NN
    short* W1f  = (short*)(IV + MROWS);        // NLAYERS*EE*E1S... = 12*180224 shorts
    short* W2f  = W1f + (size_t)NLAYERS * EE * DHID * LP;  // same byte size as before
    short* p1wb = W2f + (size_t)NLAYERS * EE * LL * DHID;  // 96*LP (K-padded)
    short* p2wb = p1wb + PP * LP;              // 192*96
    short* Tb16 = p2wb + 2 * PP * PP;          // (MROWS+64) x LP bf16 mirror of T
    short* Hs   = Tb16 + (size_t)(MROWS + 64) * LP;  // 64*NN rows + slack x DHID bf16

    prep_kernel<<<1549, 256, 0, stream>>>(x, W1, W2, p1w, p2w, MU, IV, LOSS, G0,
                                          W1f, W2f, p1wb, p2wb);
    revin_tn<<<dim3(BB, 6, 7), 256, 0, stream>>>(x, MU, IV, T, Tb16, G0);

    for (int l = 0; l < NLAYERS; ++l) {
        const float* Gcur = (l == 1) ? G1 : G0;
        float* Gnext      = (l == 1) ? G0 : G1;
        fc1_mfma<<<768, 256, 0, stream>>>(
            Tb16, W1f + (size_t)l * EE * E1S, b1 + (size_t)l * EE * DHID,
            Gcur, Gnext, wg + (size_t)l * LL * EE, wn + (size_t)l * LL * EE,
            noise + (size_t)l * BB * EE, IDX, GV, Hs, LOSS);
        fc2_fused<<<576, 256, 0, stream>>>(
            Hs, W2f + (size_t)l * EE * E2S, b2 + (size_t)l * EE * LL,
            T, Tb16, Gnext, IDX, GV, (l == NLAYERS - 1) ? 1 : 0);
    }
    proj_fused<<<321, 256, 0, stream>>>(Tb16, p1wb, p1b, p2wb, p2b, out, LOSS);
}